// Round 9
// baseline (158.385 us; speedup 1.0000x reference)
//
#include <hip/hip_runtime.h>

// Block-diagonal equivariant linear: 256x0e + 256x1o + 128x2e, B=32768, DIM=1664.
// T3+T4 cross-tile DMA pipeline with COUNTED vmcnt (never 0 in loop):
//   per step: issue global_load_lds DMA(chunk t+1) -> wait vmcnt(KW) (= newest
//   batch size, so t+1 stays in flight) -> raw s_barrier -> deint(t) (D>1) ->
//   barrier -> MFMA(t) + stores. 2 rotating fp32 L buffers + bf16 Dd tile.
// Raw barriers with memory-clobber fences; __syncthreads would emit vmcnt(0)
// and drain the pipeline. Blocks ordered [seg0|seg1|seg2] consecutive (L3).

typedef short short8 __attribute__((ext_vector_type(8)));
typedef float f32x4 __attribute__((ext_vector_type(4)));

#define DIMF 1664

__device__ __forceinline__ unsigned short f2bf(float f) {
  // round-to-nearest-even fp32 -> bf16 (finite gaussian inputs; no NaN path)
  unsigned int u = __float_as_uint(f);
  u += 0x7fffu + ((u >> 16) & 1u);
  return (unsigned short)(u >> 16);
}

__device__ __forceinline__ void gload16(const float* g, float* l) {
  // 16B/lane global -> LDS direct; dest = wave-uniform base + lane*16
  __builtin_amdgcn_global_load_lds(
      (const __attribute__((address_space(1))) void*)g,
      (__attribute__((address_space(3))) void*)l, 16, 0, 0);
}

__device__ __forceinline__ void barrier_c() {
  // cross-wave barrier with LDS-write drain; fenced so no memory op crosses
  asm volatile("s_waitcnt lgkmcnt(0)" ::: "memory");
  __builtin_amdgcn_s_barrier();
  asm volatile("" ::: "memory");
}

#define WAITVM(N) asm volatile("s_waitcnt vmcnt(%0)" ::: "memory"); // placeholder
#undef WAITVM
#define WAITVM(N) asm volatile("s_waitcnt vmcnt(%0)" :: "i"(N) : "memory")

// ws layout per segment: W[u][w] row-major; contraction over u (k), output col w (n).
// Fragment order: element ((ntg*NKS + ks)*64 + lane)*8 + j holds
//   W[k = ks*32 + (lane>>4)*8 + j][n = ntg*16 + (lane&15)] * scale  as bf16.
__global__ __launch_bounds__(256) void prep_w(const float* __restrict__ ws,
                                              unsigned short* __restrict__ wf) {
  int t = blockIdx.x * blockDim.x + threadIdx.x;  // group index, 8 bf16 per group
  int MUL, woff, goff;
  float scale;
  if (t < 8192) {
    MUL = 256; woff = 0; goff = 0; scale = 0.0625f;
  } else if (t < 16384) {
    MUL = 256; woff = 65536; goff = 8192; scale = 0.0625f;
  } else if (t < 18432) {
    MUL = 128; woff = 131072; goff = 16384; scale = 0.088388347648318447f;  // 1/sqrt(128)
  } else {
    return;
  }
  int g = t - goff;
  int l = g & 63;
  int nks = MUL >> 5;
  int ks = (g >> 6) % nks;
  int nt = g / (64 * nks);
  int n = nt * 16 + (l & 15);
  int kb = ks * 32 + (l >> 4) * 8;
  short8 v;
#pragma unroll
  for (int j = 0; j < 8; ++j)
    v[j] = (short)f2bf(ws[woff + (size_t)(kb + j) * MUL + n] * scale);
  *reinterpret_cast<short8*>(wf + (size_t)t * 8) = v;
}

// Template params: KC = u's per K-chunk; GR = batch rows per DMA group;
// GSF = f32 stride per group in L (16B-aligned, gives row padding for seg0
// read-side banks since gload_lds dests must be linear per 1KB issue).
template <int MUL, int D, int BMB, int KC, int GR, int GSF, int TPB, int S, bool BIAS>
__device__ __forceinline__ void seg_run(const float* __restrict__ x,
                                        const unsigned short* __restrict__ wf,
                                        const float* __restrict__ bs,
                                        float* __restrict__ out, int blk, char* lds) {
  constexpr int CHW = KC * D;           // f32 per row per chunk (256 / 384 / 320)
  constexpr int ISSG = GR * CHW / 256;  // 1KB issues per group (1 / 3 / 5)
  constexpr int NGRP = BMB / GR;        // groups (16 / 8 / 4)
  constexpr int NISS = NGRP * ISSG;     // issues per chunk (16 / 24 / 20)
  constexpr int KW = NISS / 4;          // issues per wave = vmcnt target (4/6/5)
  constexpr int NCH = MUL / KC;         // chunks per tile (1 / 2 / 2)
  constexpr int LSZ = NGRP * GSF;       // f32 per L buffer
  constexpr int LDAD = KC + 8;          // Dd row (u16): 272B/144B = odd*16 -> 2-way
  constexpr int MT = BMB * D;           // A rows (16 / 48 / 80), all %16==0
  constexpr int NMT = MT / 16;
  constexpr int NTW = MUL / 64;         // n-tiles/wave, 4 waves (4 / 4 / 2)
  constexpr int NKSC = KC / 32;         // k-steps per chunk (8 / 4 / 2)
  constexpr int NKS = MUL / 32;
  constexpr int NQ4 = NISS / 4;         // deint f32x4 per thread
  constexpr int STEPS = TPB * NCH;

  float* L0 = (float*)lds;
  unsigned short* Dd = (unsigned short*)(lds + 2 * LSZ * 4);

  const int tid = threadIdx.x;
  const int lane = tid & 63;
  const int wave = tid >> 6;
  const int l15 = lane & 15;
  const int lhi = lane >> 4;

  float bias[NTW];
  if (BIAS) {
#pragma unroll
    for (int nt = 0; nt < NTW; ++nt) bias[nt] = bs[wave * (MUL / 4) + nt * 16 + l15];
  }

  auto dma = [&](int st) {
    int tile = st / NCH, ch = st % NCH;
    int b0 = (blk * TPB + tile) * BMB;
    float* Lb = L0 + (st & 1) * LSZ;
#pragma unroll
    for (int m = wave; m < NISS; m += 4) {   // m wave-uniform -> LDS dest uniform
      int g2 = m / ISSG, j = m - g2 * ISSG;
      int qg = j * 256 + lane * 4;           // per-lane f32 idx within group span
      int rl = qg / CHW;
      int c = qg - rl * CHW;
      gload16(x + (size_t)(b0 + g2 * GR + rl) * DIMF + S + ch * CHW + c,
              Lb + g2 * GSF + j * 256);
    }
  };

  auto deint = [&](int st) {
    const float* Lb = L0 + (st & 1) * LSZ;
#pragma unroll
    for (int it = 0; it < NQ4; ++it) {
      int q4 = tid + it * 256;
      int m = q4 >> 6, l = q4 & 63;
      int g2 = m / ISSG, j = m - g2 * ISSG;
      f32x4 v = *reinterpret_cast<const f32x4*>(Lb + g2 * GSF + j * 256 + l * 4);
      int qg = j * 256 + l * 4;
      int rl = qg / CHW;
      int c = qg - rl * CHW;
      int u = c / D;
      int i = c - u * D;
      int rowb = (g2 * GR + rl) * D;
#pragma unroll
      for (int jj = 0; jj < 4; ++jj) {
        int ii = i + jj;
        int u2 = u;
        if (ii >= D) { ii -= D; ++u2; }  // wraps at most once (D in {3,5}, jj<4)
        Dd[(rowb + ii) * LDAD + u2] = f2bf(v[jj]);
      }
    }
  };

  f32x4 acc[NMT][NTW];

  dma(0);
#pragma unroll 1
  for (int st = 0; st < STEPS; ++st) {
    const int ch = st % NCH;
    const int tile = st / NCH;
    if (st + 1 < STEPS) {
      dma(st + 1);
      WAITVM(KW);      // chunk st landed for THIS wave; st+1 stays in flight
    } else {
      WAITVM(0);
    }
    barrier_c();       // BAR1: chunk st landed for ALL waves
    if (D > 1) {
      deint(st);
      barrier_c();     // BAR2: Dd ready; L[st&1] free for DMA(st+2)
    }
    if (ch == 0) {
#pragma unroll
      for (int a = 0; a < NMT; ++a)
#pragma unroll
        for (int b = 0; b < NTW; ++b) acc[a][b] = (f32x4){0.f, 0.f, 0.f, 0.f};
    }
    const float* Lb = L0 + (st & 1) * LSZ;
#pragma unroll
    for (int ks = 0; ks < NKSC; ++ks) {
      short8 af[NMT];
#pragma unroll
      for (int mt = 0; mt < NMT; ++mt) {
        if (D == 1) {
          const float* p = Lb + (mt * 16 + l15) * GSF + ks * 32 + lhi * 8;
          f32x4 lo = *reinterpret_cast<const f32x4*>(p);
          f32x4 hi = *reinterpret_cast<const f32x4*>(p + 4);
#pragma unroll
          for (int j = 0; j < 4; ++j) {
            af[mt][j] = (short)f2bf(lo[j]);
            af[mt][j + 4] = (short)f2bf(hi[j]);
          }
        } else {
          af[mt] = *reinterpret_cast<const short8*>(
              &Dd[(mt * 16 + l15) * LDAD + ks * 32 + lhi * 8]);
        }
      }
      int ksg = ch * NKSC + ks;
#pragma unroll
      for (int nt = 0; nt < NTW; ++nt) {
        int ntg = wave * NTW + nt;
        short8 bfr = *reinterpret_cast<const short8*>(
            wf + ((size_t)(ntg * NKS + ksg) * 64 + lane) * 8);
#pragma unroll
        for (int mt = 0; mt < NMT; ++mt)
          acc[mt][nt] = __builtin_amdgcn_mfma_f32_16x16x32_bf16(af[mt], bfr,
                                                                acc[mt][nt], 0, 0, 0);
      }
    }
    if (ch == NCH - 1) {
      // C/D layout: col = lane&15, row = (lane>>4)*4 + q
      int b0 = (blk * TPB + tile) * BMB;
#pragma unroll
      for (int nt = 0; nt < NTW; ++nt) {
        int n = wave * (MUL / 4) + nt * 16 + l15;
        float bi = BIAS ? bias[nt] : 0.f;
#pragma unroll
        for (int mt = 0; mt < NMT; ++mt)
#pragma unroll
          for (int q = 0; q < 4; ++q) {
            int mm = mt * 16 + lhi * 4 + q;
            int b = mm / D;
            int i = mm - b * D;
            out[(size_t)(b0 + b) * DIMF + S + n * D + i] = acc[mt][nt][q] + bi;
          }
      }
    }
    if (D == 1) barrier_c();  // all L reads done before DMA(st+2) overwrites
  }
}

__global__ __launch_bounds__(256) void linear_main(const float* __restrict__ x,
                                                   const unsigned short* __restrict__ wf,
                                                   const float* __restrict__ bs,
                                                   float* __restrict__ out) {
  // max over segs (seg1): 2*8*776*4 + 48*136*2 = 49664 + 13056 = 62720 B
  __shared__ __align__(16) char lds[62720];
  int blk = blockIdx.x;
  if (blk < 256) {
    // seg0: D=1, BMB=16, full-K, GSF=260 (1040B: 16B-aligned, 4-bank row step)
    seg_run<256, 1, 16, 256, 1, 260, 8, 0, true>(x, wf, bs, out, blk, lds);
  } else if (blk < 512) {
    // seg1: D=3, BMB=16, K-chunk 128 u's, 2-row groups (768 f32 -> GSF 776)
    seg_run<256, 3, 16, 128, 2, 776, 8, 256, false>(x, wf + 65536, bs, out, blk - 256,
                                                    lds);
  } else {
    // seg2: D=5, BMB=16, K-chunk 64 u's, 4-row groups (1280 f32 -> GSF 1284)
    seg_run<128, 5, 16, 64, 4, 1284, 8, 1024, false>(x, wf + 131072, bs, out,
                                                     blk - 512, lds);
  }
}

extern "C" void kernel_launch(void* const* d_in, const int* in_sizes, int n_in,
                              void* d_out, int out_size, void* d_ws, size_t ws_size,
                              hipStream_t stream) {
  const float* ws = (const float*)d_in[0];  // 147456
  const float* bs = (const float*)d_in[1];  // 256
  const float* x = (const float*)d_in[2];   // 32768 x 1664
  float* out = (float*)d_out;
  unsigned short* wf = (unsigned short*)d_ws;  // 147456 bf16 = 294912 B

  hipLaunchKernelGGL(prep_w, dim3(72), dim3(256), 0, stream, ws, wf);
  // [seg0: 256 | seg1: 256 | seg2: 256] blocks, 8 tiles each, consecutive sweep
  hipLaunchKernelGGL(linear_main, dim3(768), dim3(256), 0, stream, x, wf, bs, out);
}

// Round 10
// 125.535 us; speedup vs baseline: 1.2617x; 1.2617x over previous
//
#include <hip/hip_runtime.h>

// Block-diagonal equivariant linear: 256x0e + 256x1o + 128x2e, B=32768, DIM=1664.
// R2 one-shot-block mechanics + 8-wave blocks with B-fragments PRELOADED into
// registers (16 frags = 32 VGPR per wave, one overlapped L2 wait) so the MFMA
// loop reads only LDS + regs. Write-side deinterleave, b128 A-reads, direct
// stores, one barrier, [seg0|seg1|seg2] consecutive block order (L3 locality).

typedef short short8 __attribute__((ext_vector_type(8)));
typedef short short4v __attribute__((ext_vector_type(4)));
typedef float f32x4 __attribute__((ext_vector_type(4)));

#define DIMF 1664

__device__ __forceinline__ unsigned short f2bf(float f) {
  // round-to-nearest-even fp32 -> bf16 (finite gaussian inputs; no NaN path)
  unsigned int u = __float_as_uint(f);
  u += 0x7fffu + ((u >> 16) & 1u);
  return (unsigned short)(u >> 16);
}

// ws layout per segment: W[u][w] row-major; contraction over u (k), output col w (n).
// Fragment order: element ((ntg*NKS + ks)*64 + lane)*8 + j holds
//   W[k = ks*32 + (lane>>4)*8 + j][n = ntg*16 + (lane&15)] * scale  as bf16.
__global__ __launch_bounds__(256) void prep_w(const float* __restrict__ ws,
                                              unsigned short* __restrict__ wf) {
  int t = blockIdx.x * blockDim.x + threadIdx.x;  // group index, 8 bf16 per group
  int MUL, woff, goff;
  float scale;
  if (t < 8192) {
    MUL = 256; woff = 0; goff = 0; scale = 0.0625f;
  } else if (t < 16384) {
    MUL = 256; woff = 65536; goff = 8192; scale = 0.0625f;
  } else if (t < 18432) {
    MUL = 128; woff = 131072; goff = 16384; scale = 0.088388347648318447f;  // 1/sqrt(128)
  } else {
    return;
  }
  int g = t - goff;
  int l = g & 63;
  int nks = MUL >> 5;
  int ks = (g >> 6) % nks;
  int nt = g / (64 * nks);
  int n = nt * 16 + (l & 15);
  int kb = ks * 32 + (l >> 4) * 8;
  short8 v;
#pragma unroll
  for (int j = 0; j < 8; ++j)
    v[j] = (short)f2bf(ws[woff + (size_t)(kb + j) * MUL + n] * scale);
  *reinterpret_cast<short8*>(wf + (size_t)t * 8) = v;
}

// LDS tile: A[row = b*D+i][u] bf16, row stride LDA = MUL+8 (byte stride
// 528/272 = odd*16 -> b128 frag reads 2-way bank aliased = free).
template <int MUL, int D, int BMB, bool BIAS>
__device__ __forceinline__ void seg_run(const float* __restrict__ x,
                                        const unsigned short* __restrict__ wf,
                                        const float* __restrict__ bs,
                                        float* __restrict__ out, int blk, int s,
                                        unsigned short* A) {
  constexpr int LDA = MUL + 8;
  constexpr int MT = BMB * D;           // A rows (32 / 48 / 80), all %16 == 0
  constexpr int NMT = MT / 16;          // m-tiles (2 / 3 / 5)
  constexpr int NTW = MUL / 128;        // n-tiles per wave, 8 waves (2 / 2 / 1)
  constexpr int NKS = MUL / 32;         // k-steps (8 / 8 / 4)
  constexpr int NFR = NTW * NKS;        // B-frags per wave (16 / 16 / 4)
  constexpr int CPR = MUL * D / 4;      // f32x4 per batch row (64 / 192 / 160)
  constexpr int NG = BMB * CPR / 512;   // staged f32x4 per thread (4 / 6 / 5)

  const int tid = threadIdx.x;
  const int lane = tid & 63;
  const int wave = tid >> 6;
  const int l15 = lane & 15;
  const int lhi = lane >> 4;
  const int b0 = blk * BMB;

  // ---- B-fragment preload: issued FIRST, L2 latency overlaps x loads ----
  short8 wfr[NFR];
#pragma unroll
  for (int nt = 0; nt < NTW; ++nt)
#pragma unroll
    for (int ks = 0; ks < NKS; ++ks) {
      int ntg = wave * NTW + nt;
      wfr[nt * NKS + ks] = *reinterpret_cast<const short8*>(
          wf + ((size_t)(ntg * NKS + ks) * 64 + lane) * 8);
    }

  float bias[NTW];
  if (BIAS) {
#pragma unroll
    for (int nt = 0; nt < NTW; ++nt) bias[nt] = bs[(wave * NTW + nt) * 16 + l15];
  }

  // ---- stage x: contiguous f32x4 loads, all in flight before converts ----
  f32x4 v[NG];
#pragma unroll
  for (int it = 0; it < NG; ++it) {
    int g = tid + it * 512;
    int r = g / CPR;
    int c = (g - r * CPR) * 4;
    v[it] = *reinterpret_cast<const f32x4*>(x + (size_t)(b0 + r) * DIMF + s + c);
  }

  // ---- convert + write-side (u,i) deinterleave ----
#pragma unroll
  for (int it = 0; it < NG; ++it) {
    int g = tid + it * 512;
    int r = g / CPR;
    int c = (g - r * CPR) * 4;
    if (D == 1) {
      short4v p;
#pragma unroll
      for (int j = 0; j < 4; ++j) p[j] = (short)f2bf(v[it][j]);
      *reinterpret_cast<short4v*>(&A[r * LDA + c]) = p;
    } else {
      int u0 = c / D;
      int i0 = c - u0 * D;
#pragma unroll
      for (int j = 0; j < 4; ++j) {
        int ii = i0 + j;  // wraps at most once for D in {3,5}, j<4
        int u = u0;
        if (ii >= D) { ii -= D; ++u; }
        A[(r * D + ii) * LDA + u] = f2bf(v[it][j]);
      }
    }
  }
  __syncthreads();  // the only barrier

  // ---- MFMA: LDS + registers only (no global in loop) ----
  f32x4 acc[NMT][NTW];
#pragma unroll
  for (int a = 0; a < NMT; ++a)
#pragma unroll
    for (int b = 0; b < NTW; ++b) acc[a][b] = (f32x4){0.f, 0.f, 0.f, 0.f};
#pragma unroll
  for (int ks = 0; ks < NKS; ++ks) {
    short8 af[NMT];
#pragma unroll
    for (int mt = 0; mt < NMT; ++mt)
      af[mt] = *reinterpret_cast<const short8*>(
          &A[(mt * 16 + l15) * LDA + ks * 32 + lhi * 8]);
#pragma unroll
    for (int nt = 0; nt < NTW; ++nt)
#pragma unroll
      for (int mt = 0; mt < NMT; ++mt)
        acc[mt][nt] = __builtin_amdgcn_mfma_f32_16x16x32_bf16(af[mt], wfr[nt * NKS + ks],
                                                              acc[mt][nt], 0, 0, 0);
  }

  // ---- epilogue: C/D layout col = lane&15, row = (lane>>4)*4 + q ----
#pragma unroll
  for (int nt = 0; nt < NTW; ++nt) {
    int n = (wave * NTW + nt) * 16 + l15;
    float bi = BIAS ? bias[nt] : 0.f;
#pragma unroll
    for (int mt = 0; mt < NMT; ++mt)
#pragma unroll
      for (int q = 0; q < 4; ++q) {
        int m = mt * 16 + lhi * 4 + q;
        int b = m / D;
        int i = m - b * D;
        out[(size_t)(b0 + b) * DIMF + s + n * D + i] = acc[mt][nt][q] + bi;
      }
  }
}

__global__ __launch_bounds__(512, 4) void linear_main(const float* __restrict__ x,
                                                      const unsigned short* __restrict__ wf,
                                                      const float* __restrict__ bs,
                                                      float* __restrict__ out) {
  // max: seg1 48 rows x 264 u16 = 25344 B
  __shared__ __align__(16) unsigned short A[48 * 264];
  int blk = blockIdx.x;
  if (blk < 1024) {
    seg_run<256, 1, 32, true>(x, wf, bs, out, blk, 0, A);
  } else if (blk < 3072) {
    seg_run<256, 3, 16, false>(x, wf + 65536, bs, out, blk - 1024, 256, A);
  } else {
    seg_run<128, 5, 16, false>(x, wf + 131072, bs, out, blk - 3072, 1024, A);
  }
}

extern "C" void kernel_launch(void* const* d_in, const int* in_sizes, int n_in,
                              void* d_out, int out_size, void* d_ws, size_t ws_size,
                              hipStream_t stream) {
  const float* ws = (const float*)d_in[0];  // 147456
  const float* bs = (const float*)d_in[1];  // 256
  const float* x = (const float*)d_in[2];   // 32768 x 1664
  float* out = (float*)d_out;
  unsigned short* wf = (unsigned short*)d_ws;  // 147456 bf16 = 294912 B

  hipLaunchKernelGGL(prep_w, dim3(72), dim3(256), 0, stream, ws, wf);
  // [seg0: 1024 | seg1: 2048 | seg2: 2048] 512-thread blocks, consecutive sweep
  hipLaunchKernelGGL(linear_main, dim3(5120), dim3(512), 0, stream, x, wf, bs, out);
}